// Round 3
// baseline (2237.502 us; speedup 1.0000x reference)
//
#include <hip/hip_runtime.h>

#define SEQ   512
#define BATCH 64
#define DIM   512

typedef float  f32x4 __attribute__((ext_vector_type(4)));
typedef short  s16x8 __attribute__((ext_vector_type(8)));
typedef __bf16 bf16x2 __attribute__((ext_vector_type(2)));

__device__ __forceinline__ float bits2f(unsigned u) {
  union { unsigned u; float f; } v; v.u = u; return v.f;
}
__device__ __forceinline__ float bf2f(unsigned short h) { return bits2f((unsigned)h << 16); }
__device__ __forceinline__ float bflo(unsigned u) { return bits2f(u << 16); }
__device__ __forceinline__ float bfhi(unsigned u) { return bits2f(u & 0xFFFF0000u); }
__device__ __forceinline__ unsigned short f2bf(float f) {
  union { float f; unsigned u; } v; v.f = f;
  unsigned r = v.u + 0x7FFFu + ((v.u >> 16) & 1u);
  return (unsigned short)(r >> 16);
}
__device__ __forceinline__ unsigned packbf(float lo, float hi) {
  return (unsigned)f2bf(lo) | ((unsigned)f2bf(hi) << 16);
}
__device__ __forceinline__ float sigm(float x) { return 1.0f / (1.0f + __expf(-x)); }

// dot of two bf16 pairs accumulated into f32.  pair layout: lo16 = even k,
// hi16 = odd k.
__device__ __forceinline__ float dot2(unsigned w, unsigned h, float acc) {
#if __has_builtin(__builtin_amdgcn_fdot2_f32_bf16)
  return __builtin_amdgcn_fdot2_f32_bf16(__builtin_bit_cast(bf16x2, w),
                                         __builtin_bit_cast(bf16x2, h), acc, false);
#else
  return acc + bflo(w) * bflo(h) + bfhi(w) * bfhi(h);
#endif
}

// wave-broadcast of lane k2's value (constant k2) -> SGPR operand for dot2
__device__ __forceinline__ unsigned bcast(unsigned v, int k2) {
  return (unsigned)__builtin_amdgcn_readlane((int)v, k2);
}

// LDS-only barrier: waits LDS ops, does NOT drain vmcnt — global stores and
// prefetch loads stay in flight across it.
__device__ __forceinline__ void bar_lds() {
  asm volatile("s_waitcnt lgkmcnt(0)" ::: "memory");
  __builtin_amdgcn_s_barrier();
  asm volatile("" ::: "memory");
}

// ---------------------------------------------------------------------------
// Kernel 1: cast/pack weights (unchanged).
// ---------------------------------------------------------------------------
#define NJOBS 18
struct CastJobs {
  const float* src[NJOBS];
  const float* src2[NJOBS];
  void*        dst[NJOBS];
  int          n[NJOBS];
  int          mode[NJOBS];
  int          m[NJOBS];
  int          iN[NJOBS];
};

__global__ __launch_bounds__(256) void cast_kernel(CastJobs jobs) {
  int gsz = gridDim.x * blockDim.x;
  int gid = blockIdx.x * blockDim.x + threadIdx.x;
  for (int j = 0; j < NJOBS; ++j) {
    int n = jobs.n[j], mode = jobs.mode[j];
    int m = jobs.m[j], iN = jobs.iN[j];
    const float* s = jobs.src[j];
    if (mode == 1) {
      unsigned short* d = (unsigned short*)jobs.dst[j];
      for (int i = gid; i < n; i += gsz) {
        int k = i >> 9, nn = i & 511;
        d[nn * 512 + k] = f2bf(s[i]);
      }
    } else if (mode == 3) {
      unsigned* d = (unsigned*)jobs.dst[j];
      for (int i = gid; i < n; i += gsz) {
        int k2 = i / m, jj = i - k2 * m;
        d[i] = packbf(s[(iN + 2 * k2) * m + jj], s[(iN + 2 * k2 + 1) * m + jj]);
      }
    } else if (mode == 4) {
      unsigned* d = (unsigned*)jobs.dst[j];
      for (int i = gid; i < n; i += gsz) {
        int k2 = i >> 7, jj = i & 127;
        d[i] = packbf(s[(2 * k2) * 128 + jj], s[(2 * k2 + 1) * 128 + jj]);
      }
    } else if (mode == 5) {
      unsigned* d = (unsigned*)jobs.dst[j];
      for (int i = gid; i < n; i += gsz) {
        int k2 = i >> 7, jj = i & 127;
        d[i] = packbf(s[(iN + 2 * k2) * 128 + jj], s[(iN + 2 * k2 + 1) * 128 + jj]);
      }
    } else if (mode == 6) {
      const float* s2 = jobs.src2[j];
      unsigned short* d = (unsigned short*)jobs.dst[j];
      for (int i = gid; i < n; i += gsz) {
        int nrow = i / iN, k = i - nrow * iN;
        float v = (nrow < m) ? s[k * m + nrow] : s2[k * 128 + (nrow - m)];
        d[i] = f2bf(v);
      }
    }
  }
}

// ---------------------------------------------------------------------------
// Kernel 2: projection GEMM (bf16 MFMA) — unchanged.
// ---------------------------------------------------------------------------
__global__ __launch_bounds__(256) void proj_kernel(
    const float* __restrict__ x,
    const unsigned short* __restrict__ WbT,
    const float* __restrict__ bias0, const float* __restrict__ bias1,
    const float* __restrict__ bias2,
    unsigned short* __restrict__ p0, unsigned short* __restrict__ p1,
    unsigned short* __restrict__ p2)
{
  __shared__ __align__(16) unsigned short aS[64 * 40];
  __shared__ __align__(16) unsigned short bS[128 * 40];

  int bx = blockIdx.x;
  int nt = bx % 12, t = bx / 12;
  int wsel = nt >> 2, ncol0 = (nt & 3) * 128;
  const float* bias = (wsel == 0) ? bias0 : (wsel == 1 ? bias1 : bias2);
  unsigned short* pout = (wsel == 0) ? p0 : (wsel == 1 ? p1 : p2);

  int tid = threadIdx.x;
  int wv = tid >> 6, lane = tid & 63;
  int lq = lane & 15, quad = lane >> 4;

  f32x4 acc[8];
#pragma unroll
  for (int s = 0; s < 8; ++s) acc[s] = (f32x4){0.f, 0.f, 0.f, 0.f};

  int arow = tid >> 2, ak0 = (tid & 3) * 8;
  const float* asrc0 = x + ((size_t)arow * SEQ + t) * DIM + ak0;
  int brow = tid >> 1, bk0 = (tid & 1) * 16;
  const unsigned short* bsrc0 =
      WbT + ((size_t)(wsel * 512 + ncol0 + brow)) * 512 + bk0;

  for (int kk = 0; kk < 16; ++kk) {
    const float* asrc = asrc0 + kk * 32;
    float4 f0 = *(const float4*)(asrc);
    float4 f1 = *(const float4*)(asrc + 4);
    uint4 av;
    av.x = packbf(f0.x, f0.y);
    av.y = packbf(f0.z, f0.w);
    av.z = packbf(f1.x, f1.y);
    av.w = packbf(f1.z, f1.w);
    *(uint4*)(aS + arow * 40 + ak0) = av;
    const unsigned short* bsrc = bsrc0 + kk * 32;
    *(uint4*)(bS + brow * 40 + bk0)     = *(const uint4*)(bsrc);
    *(uint4*)(bS + brow * 40 + bk0 + 8) = *(const uint4*)(bsrc + 8);
    __syncthreads();

    s16x8 af = *(const s16x8*)(aS + (wv * 16 + lq) * 40 + quad * 8);
#pragma unroll
    for (int s = 0; s < 8; ++s) {
      s16x8 bf = *(const s16x8*)(bS + (s * 16 + lq) * 40 + quad * 8);
      acc[s] = __builtin_amdgcn_mfma_f32_16x16x32_bf16(af, bf, acc[s], 0, 0, 0);
    }
    __syncthreads();
  }

#pragma unroll
  for (int s = 0; s < 8; ++s) {
    int col = ncol0 + s * 16 + lq;
    float bv = bias[col];
#pragma unroll
    for (int v = 0; v < 4; ++v) {
      int b = wv * 16 + quad * 4 + v;
      pout[((size_t)(t * BATCH + b)) * DIM + col] = f2bf(acc[s][v] + bv);
    }
  }
}

// ---------------------------------------------------------------------------
// Kernel 3: base GEMM for block I (unchanged).
// ---------------------------------------------------------------------------
template<int I>
__global__ __launch_bounds__(256) void base_gemm(
    const float* __restrict__ outp,
    const unsigned short* __restrict__ Bcat,
    unsigned short* __restrict__ baseO)
{
  constexpr int KI  = 4 * I;
  constexpr int K   = 128 * I;
  constexpr int NT  = I + 2;
  constexpr int NW  = NT * 128;
  constexpr int PER = 1 << I;

  __shared__ __align__(16) unsigned short aS[64 * 40];
  __shared__ __align__(16) unsigned short bS[128 * 40];

  int bx = blockIdx.x;
  int nt = bx % NT, n = bx / NT;
  int ncol0 = nt * 128;

  int tid = threadIdx.x;
  int wv = tid >> 6, lane = tid & 63;
  int lq = lane & 15, quad = lane >> 4;

  f32x4 acc[8];
#pragma unroll
  for (int s = 0; s < 8; ++s) acc[s] = (f32x4){0.f, 0.f, 0.f, 0.f};

  int arow = tid >> 2, ak0 = (tid & 3) * 8;
  const float* asrc0 = outp + ((size_t)arow * SEQ + (n * PER - 1)) * DIM + ak0;
  int brow = tid >> 1, bk0 = (tid & 1) * 16;
  const unsigned short* bsrc0 = Bcat + (size_t)(ncol0 + brow) * K + bk0;

  for (int kk = 0; kk < KI; ++kk) {
    uint4 av;
    if (n > 0) {
      const float* asrc = asrc0 + kk * 32;
      float4 f0 = *(const float4*)(asrc);
      float4 f1 = *(const float4*)(asrc + 4);
      av.x = packbf(f0.x, f0.y);
      av.y = packbf(f0.z, f0.w);
      av.z = packbf(f1.x, f1.y);
      av.w = packbf(f1.z, f1.w);
    } else {
      av = (uint4){0u, 0u, 0u, 0u};
    }
    *(uint4*)(aS + arow * 40 + ak0) = av;
    const unsigned short* bsrc = bsrc0 + kk * 32;
    *(uint4*)(bS + brow * 40 + bk0)     = *(const uint4*)(bsrc);
    *(uint4*)(bS + brow * 40 + bk0 + 8) = *(const uint4*)(bsrc + 8);
    __syncthreads();

    s16x8 af = *(const s16x8*)(aS + (wv * 16 + lq) * 40 + quad * 8);
#pragma unroll
    for (int s = 0; s < 8; ++s) {
      s16x8 bf = *(const s16x8*)(bS + (s * 16 + lq) * 40 + quad * 8);
      acc[s] = __builtin_amdgcn_mfma_f32_16x16x32_bf16(af, bf, acc[s], 0, 0, 0);
    }
    __syncthreads();
  }

#pragma unroll
  for (int s = 0; s < 8; ++s) {
    int col = ncol0 + s * 16 + lq;
#pragma unroll
    for (int v = 0; v < 4; ++v) {
      int bb = wv * 16 + quad * 4 + v;
      baseO[(size_t)(n * 64 + bb) * NW + col] = f2bf(acc[s][v]);
    }
  }
}

// ---------------------------------------------------------------------------
// Kernel 4: scan phase, readlane-broadcast design.
// NW = M+128 threads; threads [0,M) = r/h threads, [M,NW) = z threads.
// Per step:
//  A: r-threads: 64 dot2 (wr pinned VGPR x readlane-broadcast h) -> u; pack uX
//     z-threads: 64 dot2 -> zX.                         [bar1]
//  B: r-threads: 64 dot2 on u-slice q=t>>7 (wh pinned x readlane-broadcast u)
//     partials for q>0 -> partX.                        [bar2 if I>=1]
//  F: t<128: reduce partials, sigmoid, blend, write hF/hX/out.  [bar3]
//     all: refresh hpk = hX[lane].
// LDS ops per wave per step: ~5 (was ~130) -> no longer LDS-pipe-bound.
// Weights pinned to ArchVGPRs via asm (max 128/thread, fits 256-reg limit).
// ---------------------------------------------------------------------------
template<int I>
__global__ __launch_bounds__((I + 2) * 128, (I == 3) ? 3 : ((I >= 1) ? 2 : 1))
void scan_rl(const unsigned short* __restrict__ px,
             const unsigned short* __restrict__ pr,
             const unsigned short* __restrict__ pz,
             const unsigned* __restrict__ crpk,
             const unsigned* __restrict__ czpk,
             const unsigned* __restrict__ chpk,
             const unsigned short* __restrict__ base,
             float* __restrict__ out)
{
  constexpr int M    = (I + 1) * 128;
  constexpr int IN   = I * 128;
  constexpr int PER  = 1 << I;
  constexpr int U    = 512 >> I;
  constexpr int NW   = M + 128;
  constexpr int SPL2 = I + 1;          // h k-slices

  __shared__ float    hF[128];
  __shared__ unsigned hX[64];
  __shared__ unsigned uX[M / 2];
  __shared__ float    zX[128];
  __shared__ float    partX[(SPL2 > 1) ? (SPL2 - 1) * 128 : 1];

  const int  b   = blockIdx.x;
  const int  t   = threadIdx.x;
  const bool isR = (t < M);            // wave-uniform (M multiple of 128)
  const int  jz  = t - M;
  const int  q   = t >> 7;             // h slice (wave-pair uniform)
  const bool isF = (t < 128);

  // ---- weights -> pinned ArchVGPRs (loop-invariant, forced resident)
  unsigned wr[64], wh[64], wz[64];
  if (isR) {
#pragma unroll
    for (int k2 = 0; k2 < 64; ++k2) wr[k2] = crpk[k2 * M + t];
#pragma unroll
    for (int k2 = 0; k2 < 64; ++k2) asm volatile("" : "+v"(wr[k2]));
#pragma unroll
    for (int k2 = 0; k2 < 64; ++k2) wh[k2] = chpk[(q * 64 + k2) * 128 + (t & 127)];
#pragma unroll
    for (int k2 = 0; k2 < 64; ++k2) asm volatile("" : "+v"(wh[k2]));
  } else {
#pragma unroll
    for (int k2 = 0; k2 < 64; ++k2) wz[k2] = czpk[k2 * 128 + jz];
#pragma unroll
    for (int k2 = 0; k2 < 64; ++k2) asm volatile("" : "+v"(wz[k2]));
  }

  if (isF) hF[t] = 0.f;
  unsigned hpk = 0u;    // lane l holds packed h pair l (all waves replicate)
  float vprev = 0.f;

  // ---- prologue prefetch (iteration 0) + running pointers
  constexpr size_t STRD = (size_t)PER * BATCH * DIM;
  unsigned short f_pr = 0, f_br = 0, f_pz = 0, f_bz = 0, f_px = 0;
  float f_pv = 0.f;
  const unsigned short* prp = nullptr;
  const unsigned short* pxp = nullptr;
  const unsigned short* pzp = nullptr;
  const unsigned short* bsp = nullptr;
  const float* pvp = nullptr;
  if (isR) {
    f_pr = pr[(size_t)b * DIM + t];
    prp  = pr + ((size_t)PER * BATCH + b) * DIM + t;
    if constexpr (I > 0) {
      f_br = base[(size_t)b * NW + t];
      bsp  = base + ((size_t)64 + b) * NW + t;
      if (t < IN) pvp = out + ((size_t)b * SEQ + (PER - 1)) * DIM + t;
    }
    if (isF) {
      f_px = px[(size_t)b * DIM + IN + t];
      pxp  = px + ((size_t)PER * BATCH + b) * DIM + IN + t;
    }
  } else {
    f_pz = pz[(size_t)b * DIM + IN + jz];
    pzp  = pz + ((size_t)PER * BATCH + b) * DIM + IN + jz;
    if constexpr (I > 0) {
      f_bz = base[(size_t)b * NW + M + jz];
      bsp  = base + ((size_t)64 + b) * NW + M + jz;
    }
  }
  float* op = out + (size_t)b * SEQ * DIM + IN + (isF ? t : 0);

  bar_lds();  // hF zeros visible

  for (int n = 0; n < U; ++n) {
    const unsigned short c_pr = f_pr, c_br = f_br, c_pz = f_pz, c_bz = f_bz,
                         c_px = f_px;
    const float c_pv = f_pv;

    // ---- issue prefetch for next iteration (stays in flight across bars)
    if (n + 1 < U) {
      if (isR) {
        f_pr = *prp; prp += STRD;
        if constexpr (I > 0) {
          f_br = *bsp; bsp += (size_t)64 * NW;
          if (t < IN) { f_pv = *pvp; pvp += (size_t)PER * DIM; }
        }
        if (isF) { f_px = *pxp; pxp += STRD; }
      } else {
        f_pz = *pzp; pzp += STRD;
        if constexpr (I > 0) { f_bz = *bsp; bsp += (size_t)64 * NW; }
      }
    }

    // ---------------- phase A: r and z gates ----------------
    if (isR) {
      float a0 = 0.f, a1 = 0.f, a2 = 0.f, a3 = 0.f;
#pragma unroll
      for (int k2 = 0; k2 < 64; k2 += 4) {
        a0 = dot2(wr[k2],     bcast(hpk, k2),     a0);
        a1 = dot2(wr[k2 + 1], bcast(hpk, k2 + 1), a1);
        a2 = dot2(wr[k2 + 2], bcast(hpk, k2 + 2), a2);
        a3 = dot2(wr[k2 + 3], bcast(hpk, k2 + 3), a3);
      }
      float ar = bf2f(c_pr) + (a0 + a1) + (a2 + a3);
      if constexpr (I > 0) ar += bf2f(c_br);
      const float r = sigm(ar);
      float hp;
      if constexpr (I == 0) hp = hF[t];
      else hp = (t >= IN) ? hF[t - IN] : c_pv;
      const float u  = r * hp;
      const float uo = __shfl_xor(u, 1);
      if (!(t & 1)) uX[t >> 1] = packbf(u, uo);
    } else {
      float a0 = 0.f, a1 = 0.f, a2 = 0.f, a3 = 0.f;
#pragma unroll
      for (int k2 = 0; k2 < 64; k2 += 4) {
        a0 = dot2(wz[k2],     bcast(hpk, k2),     a0);
        a1 = dot2(wz[k2 + 1], bcast(hpk, k2 + 1), a1);
        a2 = dot2(wz[k2 + 2], bcast(hpk, k2 + 2), a2);
        a3 = dot2(wz[k2 + 3], bcast(hpk, k2 + 3), a3);
      }
      float zp = bf2f(c_pz) + (a0 + a1) + (a2 + a3);
      if constexpr (I > 0) zp += bf2f(c_bz);
      zX[jz] = sigm(zp);
    }
    bar_lds();  // bar1: uX, zX ready

    // ---------------- phase B: candidate matvec on u ----------------
    float ah = 0.f;
    if (isR) {
      const unsigned upk = uX[(q << 6) | (t & 63)];  // lane-indexed slice q
      float a0 = 0.f, a1 = 0.f, a2 = 0.f, a3 = 0.f;
#pragma unroll
      for (int k2 = 0; k2 < 64; k2 += 4) {
        a0 = dot2(wh[k2],     bcast(upk, k2),     a0);
        a1 = dot2(wh[k2 + 1], bcast(upk, k2 + 1), a1);
        a2 = dot2(wh[k2 + 2], bcast(upk, k2 + 2), a2);
        a3 = dot2(wh[k2 + 3], bcast(upk, k2 + 3), a3);
      }
      ah = (a0 + a1) + (a2 + a3);
      if constexpr (SPL2 > 1) {
        if (q > 0) partX[(q - 1) * 128 + (t & 127)] = ah;
      }
    }
    if constexpr (SPL2 > 1) bar_lds();  // bar2: partials ready

    // ---------------- finalize ----------------
    if (isF) {
      float tot = ah;
      if constexpr (SPL2 > 1) {
#pragma unroll
        for (int j = 1; j < SPL2; ++j) tot += partX[(j - 1) * 128 + t];
      }
      const float hnew = sigm(tot + bf2f(c_px));
      const float z    = zX[t];
      const float v    = z * hnew + (1.f - z) * vprev;
      vprev = v;
      hF[t] = v;
      const float vo = __shfl_xor(v, 1);
      if (!(t & 1)) hX[t >> 1] = packbf(v, vo);
#pragma unroll
      for (int p = 0; p < PER; ++p) op[p * DIM] = v;
    }
    op += (size_t)PER * DIM;
    bar_lds();  // bar3: hF/hX ready
    hpk = hX[t & 63];
  }
}

// ---------------------------------------------------------------------------
// Host launcher
// ---------------------------------------------------------------------------
extern "C" void kernel_launch(void* const* d_in, const int* in_sizes, int n_in,
                              void* d_out, int out_size, void* d_ws, size_t ws_size,
                              hipStream_t stream) {
  (void)in_sizes; (void)n_in; (void)out_size; (void)ws_size;

  const float* x  = (const float*)d_in[0];
  const float* W  = (const float*)d_in[1];
  const float* bb = (const float*)d_in[2];
  const float* Wr = (const float*)d_in[3];
  const float* br = (const float*)d_in[4];
  const float* Wz = (const float*)d_in[5];
  const float* bz = (const float*)d_in[6];
  const float* ch_[4]; const float* cr_[4]; const float* cz_[4];
  for (int i = 0; i < 4; ++i) {
    ch_[i] = (const float*)d_in[7 + 3 * i];
    cr_[i] = (const float*)d_in[8 + 3 * i];
    cz_[i] = (const float*)d_in[9 + 3 * i];
  }

  char* ws = (char*)d_ws;
  size_t off = 0;
  auto alloc = [&](size_t bytes) -> void* {
    void* p = ws + off;
    off += (bytes + 255) & ~(size_t)255;
    return p;
  };

  unsigned short* WbT = (unsigned short*)alloc(3ull * 512 * 512 * 2);
  unsigned* Crpk[4]; unsigned* Chpk[4]; unsigned* Czpk[4];
  unsigned short* Bcat[4] = {nullptr, nullptr, nullptr, nullptr};
  for (int i = 0; i < 4; ++i) {
    int m = (i + 1) * 128;
    Crpk[i] = (unsigned*)alloc((size_t)64 * m * 4);
    Chpk[i] = (unsigned*)alloc((size_t)(m / 2) * 128 * 4);
    Czpk[i] = (unsigned*)alloc((size_t)64 * 128 * 4);
  }
  for (int i = 1; i < 4; ++i) {
    int m = (i + 1) * 128, iN = i * 128;
    Bcat[i] = (unsigned short*)alloc((size_t)(m + 128) * iN * 2);
  }
  unsigned short* p0 = (unsigned short*)alloc((size_t)SEQ * BATCH * DIM * 2);
  unsigned short* p1 = (unsigned short*)alloc((size_t)SEQ * BATCH * DIM * 2);
  unsigned short* p2 = (unsigned short*)alloc((size_t)SEQ * BATCH * DIM * 2);
  unsigned short* baseB = (unsigned short*)alloc((size_t)16384 * 384 * 2);  // max of G1..G3
  // total ~117 MB

  // ---- cast/pack jobs
  CastJobs jobs{};
  int jn = 0;
  const float* wsrc[3] = {W, Wr, Wz};
  for (int j = 0; j < 3; ++j) {
    jobs.src[jn] = wsrc[j]; jobs.dst[jn] = WbT + (size_t)j * 512 * 512;
    jobs.n[jn] = 512 * 512; jobs.mode[jn] = 1; jobs.m[jn] = 512; jobs.iN[jn] = 0; jn++;
  }
  for (int i = 0; i < 4; ++i) {
    int m = (i + 1) * 128, iN = i * 128;
    jobs.src[jn] = cr_[i]; jobs.dst[jn] = Crpk[i];
    jobs.n[jn] = 64 * m; jobs.mode[jn] = 3; jobs.m[jn] = m; jobs.iN[jn] = iN; jn++;
    jobs.src[jn] = ch_[i]; jobs.dst[jn] = Chpk[i];
    jobs.n[jn] = (m / 2) * 128; jobs.mode[jn] = 4; jobs.m[jn] = m; jobs.iN[jn] = iN; jn++;
    jobs.src[jn] = cz_[i]; jobs.dst[jn] = Czpk[i];
    jobs.n[jn] = 64 * 128; jobs.mode[jn] = 5; jobs.m[jn] = m; jobs.iN[jn] = iN; jn++;
  }
  for (int i = 1; i < 4; ++i) {
    int m = (i + 1) * 128, iN = i * 128;
    jobs.src[jn] = cr_[i]; jobs.src2[jn] = cz_[i]; jobs.dst[jn] = Bcat[i];
    jobs.n[jn] = (m + 128) * iN; jobs.mode[jn] = 6; jobs.m[jn] = m; jobs.iN[jn] = iN; jn++;
  }
  cast_kernel<<<256, 256, 0, stream>>>(jobs);

  // ---- projections
  proj_kernel<<<SEQ * 12, 256, 0, stream>>>(x, WbT, bb, br, bz, p0, p1, p2);

  float* outp = (float*)d_out;

  // ---- cascade: B0 -> G1 -> B1 -> G2 -> B2 -> G3 -> B3
  scan_rl<0><<<64, 256, 0, stream>>>(p0, p1, p2, Crpk[0], Czpk[0], Chpk[0],
                                     nullptr, outp);
  base_gemm<1><<<256 * 3, 256, 0, stream>>>(outp, Bcat[1], baseB);
  scan_rl<1><<<64, 384, 0, stream>>>(p0, p1, p2, Crpk[1], Czpk[1], Chpk[1],
                                     baseB, outp);
  base_gemm<2><<<128 * 4, 256, 0, stream>>>(outp, Bcat[2], baseB);
  scan_rl<2><<<64, 512, 0, stream>>>(p0, p1, p2, Crpk[2], Czpk[2], Chpk[2],
                                     baseB, outp);
  base_gemm<3><<<64 * 5, 256, 0, stream>>>(outp, Bcat[3], baseB);
  scan_rl<3><<<64, 640, 0, stream>>>(p0, p1, p2, Crpk[3], Czpk[3], Chpk[3],
                                     baseB, outp);
}

// Round 5
// 1969.820 us; speedup vs baseline: 1.1359x; 1.1359x over previous
//
#include <hip/hip_runtime.h>

#define SEQ   512
#define BATCH 64
#define DIM   512

typedef float  f32x4 __attribute__((ext_vector_type(4)));
typedef short  s16x8 __attribute__((ext_vector_type(8)));
typedef __bf16 bf16x2 __attribute__((ext_vector_type(2)));

__device__ __forceinline__ float bits2f(unsigned u) {
  union { unsigned u; float f; } v; v.u = u; return v.f;
}
__device__ __forceinline__ float bf2f(unsigned short h) { return bits2f((unsigned)h << 16); }
__device__ __forceinline__ float bflo(unsigned u) { return bits2f(u << 16); }
__device__ __forceinline__ float bfhi(unsigned u) { return bits2f(u & 0xFFFF0000u); }
__device__ __forceinline__ unsigned short f2bf(float f) {
  union { float f; unsigned u; } v; v.f = f;
  unsigned r = v.u + 0x7FFFu + ((v.u >> 16) & 1u);
  return (unsigned short)(r >> 16);
}
__device__ __forceinline__ unsigned packbf(float lo, float hi) {
  return (unsigned)f2bf(lo) | ((unsigned)f2bf(hi) << 16);
}
__device__ __forceinline__ float sigm(float x) { return 1.0f / (1.0f + __expf(-x)); }

// dot of two bf16 pairs accumulated into f32.  pair layout: lo16 = even k,
// hi16 = odd k.
__device__ __forceinline__ float dot2(unsigned w, unsigned h, float acc) {
#if __has_builtin(__builtin_amdgcn_fdot2_f32_bf16)
  return __builtin_amdgcn_fdot2_f32_bf16(__builtin_bit_cast(bf16x2, w),
                                         __builtin_bit_cast(bf16x2, h), acc, false);
#else
  return acc + bflo(w) * bflo(h) + bfhi(w) * bfhi(h);
#endif
}

// wave-broadcast of lane k2's value (constant k2) via v_readlane -> SGPR.
// VALU-pipe broadcast: scales with 4 SIMDs/CU, unlike the per-CU DS pipe.
__device__ __forceinline__ unsigned bcast(unsigned v, int k2) {
  return (unsigned)__builtin_amdgcn_readlane((int)v, k2);
}

// LDS-only barrier: waits LDS ops, does NOT drain vmcnt — global stores and
// prefetch loads stay in flight across it.
__device__ __forceinline__ void bar_lds() {
  asm volatile("s_waitcnt lgkmcnt(0)" ::: "memory");
  __builtin_amdgcn_s_barrier();
  asm volatile("" ::: "memory");
}

// ---------------------------------------------------------------------------
// Kernel 1: cast/pack weights (unchanged).
// ---------------------------------------------------------------------------
#define NJOBS 18
struct CastJobs {
  const float* src[NJOBS];
  const float* src2[NJOBS];
  void*        dst[NJOBS];
  int          n[NJOBS];
  int          mode[NJOBS];
  int          m[NJOBS];
  int          iN[NJOBS];
};

__global__ __launch_bounds__(256) void cast_kernel(CastJobs jobs) {
  int gsz = gridDim.x * blockDim.x;
  int gid = blockIdx.x * blockDim.x + threadIdx.x;
  for (int j = 0; j < NJOBS; ++j) {
    int n = jobs.n[j], mode = jobs.mode[j];
    int m = jobs.m[j], iN = jobs.iN[j];
    const float* s = jobs.src[j];
    if (mode == 1) {
      unsigned short* d = (unsigned short*)jobs.dst[j];
      for (int i = gid; i < n; i += gsz) {
        int k = i >> 9, nn = i & 511;
        d[nn * 512 + k] = f2bf(s[i]);
      }
    } else if (mode == 3) {
      unsigned* d = (unsigned*)jobs.dst[j];
      for (int i = gid; i < n; i += gsz) {
        int k2 = i / m, jj = i - k2 * m;
        d[i] = packbf(s[(iN + 2 * k2) * m + jj], s[(iN + 2 * k2 + 1) * m + jj]);
      }
    } else if (mode == 4) {
      unsigned* d = (unsigned*)jobs.dst[j];
      for (int i = gid; i < n; i += gsz) {
        int k2 = i >> 7, jj = i & 127;
        d[i] = packbf(s[(2 * k2) * 128 + jj], s[(2 * k2 + 1) * 128 + jj]);
      }
    } else if (mode == 5) {
      unsigned* d = (unsigned*)jobs.dst[j];
      for (int i = gid; i < n; i += gsz) {
        int k2 = i >> 7, jj = i & 127;
        d[i] = packbf(s[(iN + 2 * k2) * 128 + jj], s[(iN + 2 * k2 + 1) * 128 + jj]);
      }
    } else if (mode == 6) {
      const float* s2 = jobs.src2[j];
      unsigned short* d = (unsigned short*)jobs.dst[j];
      for (int i = gid; i < n; i += gsz) {
        int nrow = i / iN, k = i - nrow * iN;
        float v = (nrow < m) ? s[k * m + nrow] : s2[k * 128 + (nrow - m)];
        d[i] = f2bf(v);
      }
    }
  }
}

// ---------------------------------------------------------------------------
// Kernel 2: projection GEMM (bf16 MFMA) — unchanged.
// ---------------------------------------------------------------------------
__global__ __launch_bounds__(256) void proj_kernel(
    const float* __restrict__ x,
    const unsigned short* __restrict__ WbT,
    const float* __restrict__ bias0, const float* __restrict__ bias1,
    const float* __restrict__ bias2,
    unsigned short* __restrict__ p0, unsigned short* __restrict__ p1,
    unsigned short* __restrict__ p2)
{
  __shared__ __align__(16) unsigned short aS[64 * 40];
  __shared__ __align__(16) unsigned short bS[128 * 40];

  int bx = blockIdx.x;
  int nt = bx % 12, t = bx / 12;
  int wsel = nt >> 2, ncol0 = (nt & 3) * 128;
  const float* bias = (wsel == 0) ? bias0 : (wsel == 1 ? bias1 : bias2);
  unsigned short* pout = (wsel == 0) ? p0 : (wsel == 1 ? p1 : p2);

  int tid = threadIdx.x;
  int wv = tid >> 6, lane = tid & 63;
  int lq = lane & 15, quad = lane >> 4;

  f32x4 acc[8];
#pragma unroll
  for (int s = 0; s < 8; ++s) acc[s] = (f32x4){0.f, 0.f, 0.f, 0.f};

  int arow = tid >> 2, ak0 = (tid & 3) * 8;
  const float* asrc0 = x + ((size_t)arow * SEQ + t) * DIM + ak0;
  int brow = tid >> 1, bk0 = (tid & 1) * 16;
  const unsigned short* bsrc0 =
      WbT + ((size_t)(wsel * 512 + ncol0 + brow)) * 512 + bk0;

  for (int kk = 0; kk < 16; ++kk) {
    const float* asrc = asrc0 + kk * 32;
    float4 f0 = *(const float4*)(asrc);
    float4 f1 = *(const float4*)(asrc + 4);
    uint4 av;
    av.x = packbf(f0.x, f0.y);
    av.y = packbf(f0.z, f0.w);
    av.z = packbf(f1.x, f1.y);
    av.w = packbf(f1.z, f1.w);
    *(uint4*)(aS + arow * 40 + ak0) = av;
    const unsigned short* bsrc = bsrc0 + kk * 32;
    *(uint4*)(bS + brow * 40 + bk0)     = *(const uint4*)(bsrc);
    *(uint4*)(bS + brow * 40 + bk0 + 8) = *(const uint4*)(bsrc + 8);
    __syncthreads();

    s16x8 af = *(const s16x8*)(aS + (wv * 16 + lq) * 40 + quad * 8);
#pragma unroll
    for (int s = 0; s < 8; ++s) {
      s16x8 bf = *(const s16x8*)(bS + (s * 16 + lq) * 40 + quad * 8);
      acc[s] = __builtin_amdgcn_mfma_f32_16x16x32_bf16(af, bf, acc[s], 0, 0, 0);
    }
    __syncthreads();
  }

#pragma unroll
  for (int s = 0; s < 8; ++s) {
    int col = ncol0 + s * 16 + lq;
    float bv = bias[col];
#pragma unroll
    for (int v = 0; v < 4; ++v) {
      int b = wv * 16 + quad * 4 + v;
      pout[((size_t)(t * BATCH + b)) * DIM + col] = f2bf(acc[s][v] + bv);
    }
  }
}

// ---------------------------------------------------------------------------
// Kernel 3: base GEMM for block I (unchanged).
// ---------------------------------------------------------------------------
template<int I>
__global__ __launch_bounds__(256) void base_gemm(
    const float* __restrict__ outp,
    const unsigned short* __restrict__ Bcat,
    unsigned short* __restrict__ baseO)
{
  constexpr int KI  = 4 * I;
  constexpr int K   = 128 * I;
  constexpr int NT  = I + 2;
  constexpr int NW  = NT * 128;
  constexpr int PER = 1 << I;

  __shared__ __align__(16) unsigned short aS[64 * 40];
  __shared__ __align__(16) unsigned short bS[128 * 40];

  int bx = blockIdx.x;
  int nt = bx % NT, n = bx / NT;
  int ncol0 = nt * 128;

  int tid = threadIdx.x;
  int wv = tid >> 6, lane = tid & 63;
  int lq = lane & 15, quad = lane >> 4;

  f32x4 acc[8];
#pragma unroll
  for (int s = 0; s < 8; ++s) acc[s] = (f32x4){0.f, 0.f, 0.f, 0.f};

  int arow = tid >> 2, ak0 = (tid & 3) * 8;
  const float* asrc0 = outp + ((size_t)arow * SEQ + (n * PER - 1)) * DIM + ak0;
  int brow = tid >> 1, bk0 = (tid & 1) * 16;
  const unsigned short* bsrc0 = Bcat + (size_t)(ncol0 + brow) * K + bk0;

  for (int kk = 0; kk < KI; ++kk) {
    uint4 av;
    if (n > 0) {
      const float* asrc = asrc0 + kk * 32;
      float4 f0 = *(const float4*)(asrc);
      float4 f1 = *(const float4*)(asrc + 4);
      av.x = packbf(f0.x, f0.y);
      av.y = packbf(f0.z, f0.w);
      av.z = packbf(f1.x, f1.y);
      av.w = packbf(f1.z, f1.w);
    } else {
      av = (uint4){0u, 0u, 0u, 0u};
    }
    *(uint4*)(aS + arow * 40 + ak0) = av;
    const unsigned short* bsrc = bsrc0 + kk * 32;
    *(uint4*)(bS + brow * 40 + bk0)     = *(const uint4*)(bsrc);
    *(uint4*)(bS + brow * 40 + bk0 + 8) = *(const uint4*)(bsrc + 8);
    __syncthreads();

    s16x8 af = *(const s16x8*)(aS + (wv * 16 + lq) * 40 + quad * 8);
#pragma unroll
    for (int s = 0; s < 8; ++s) {
      s16x8 bf = *(const s16x8*)(bS + (s * 16 + lq) * 40 + quad * 8);
      acc[s] = __builtin_amdgcn_mfma_f32_16x16x32_bf16(af, bf, acc[s], 0, 0, 0);
    }
    __syncthreads();
  }

#pragma unroll
  for (int s = 0; s < 8; ++s) {
    int col = ncol0 + s * 16 + lq;
#pragma unroll
    for (int v = 0; v < 4; ++v) {
      int bb = wv * 16 + quad * 4 + v;
      baseO[(size_t)(n * 64 + bb) * NW + col] = f2bf(acc[s][v]);
    }
  }
}

// ---------------------------------------------------------------------------
// Kernel 4: scan phase, ONE-weight-array-per-thread + readlane broadcast.
// Roles (wave-aligned):  t<M: r-col t  |  t<M+128: z-col  |  rest: h-slices.
//   Every thread owns exactly ONE w[64] array (role-dependent source) ->
//   ~100 live VGPRs, resident under all caps.  State broadcast = v_readlane
//   (VALU pipe, per-SIMD) instead of uniform ds_read (per-CU DS pipe).
// Per step: A: rz-threads 64 dots on hpk -> uX/zX. bar1.
//           B: h-threads 64 dots on their uX slice -> partials. [barB]
//           F: slice-0 reduces, sigmoid, blend, writes hF/hX/out. bar2.
// R4->R5 fix: pv prefetch was shifted one PER (n=0 must see h(-1)=0; the
// value for iteration n+1 is out row (n+1)*PER-1, loaded during iter n).
// ---------------------------------------------------------------------------
template<int I>
__global__ __launch_bounds__(128 * (2 * I + 3), (I == 0) ? 2 : (I == 1 ? 3 : 4))
void scan_rl2(const unsigned short* __restrict__ px,
              const unsigned short* __restrict__ pr,
              const unsigned short* __restrict__ pz,
              const unsigned* __restrict__ crpk,
              const unsigned* __restrict__ czpk,
              const unsigned* __restrict__ chpk,
              const unsigned short* __restrict__ base,
              float* __restrict__ out)
{
  constexpr int M   = (I + 1) * 128;
  constexpr int IN  = I * 128;
  constexpr int PER = 1 << I;
  constexpr int U   = 512 >> I;
  constexpr int NW  = M + 128;
  constexpr int NSL = I + 1;           // h k-slices

  __shared__ float    hF[128];         // own-block state, f32
  __shared__ unsigned hX[64];          // own-block state, packed bf16 pairs
  __shared__ unsigned uX[M / 2];       // u, packed pairs
  __shared__ float    zX[128];
  __shared__ float    partX[(NSL > 1) ? (NSL - 1) * 128 : 1];

  const int  b    = blockIdx.x;
  const int  t    = threadIdx.x;
  const bool isRZ = (t < M + 128);
  const bool isR  = (t < M);
  const int  jz   = t - M;                 // z col (z-threads)
  const int  hidx = t - (M + 128);         // h-thread index
  const int  q    = hidx >> 7;             // h slice
  const int  jj   = hidx & 127;            // h col
  const bool isF  = (!isRZ) && (q == 0);   // finalizer

  // ---- exactly ONE weight array per thread (all sources index k2*S + O)
  const unsigned* wsrc;
  int wS, wO;
  if (isR)       { wsrc = crpk; wS = M;   wO = t; }
  else if (isRZ) { wsrc = czpk; wS = 128; wO = jz; }
  else           { wsrc = chpk; wS = 128; wO = q * 8192 + jj; }
  unsigned w[64];
#pragma unroll
  for (int k2 = 0; k2 < 64; ++k2) w[k2] = wsrc[(size_t)k2 * wS + wO];

  if (t < 128) hF[t] = 0.f;
  if (t < 64)  hX[t] = 0u;
  float vprev = 0.f;

  // ---- prologue prefetch + running pointers (role-specific)
  constexpr size_t STRD = (size_t)PER * BATCH * DIM;
  unsigned short f_p = 0, f_b = 0;
  float f_pv = 0.f;
  const unsigned short* pp = nullptr;
  const unsigned short* bp = nullptr;
  const float* vp = nullptr;
  if (isR) {
    f_p = pr[(size_t)b * DIM + t];
    pp  = pr + ((size_t)PER * BATCH + b) * DIM + t;
    if constexpr (I > 0) {
      f_b = base[(size_t)b * NW + t];
      bp  = base + ((size_t)64 + b) * NW + t;
      if (t < IN) {
        f_pv = 0.f;  // h at time -1 is zero (used at n=0)
        vp   = out + ((size_t)b * SEQ + (PER - 1)) * DIM + t;  // value for n=1
      }
    }
  } else if (isRZ) {
    f_p = pz[(size_t)b * DIM + IN + jz];
    pp  = pz + ((size_t)PER * BATCH + b) * DIM + IN + jz;
    if constexpr (I > 0) {
      f_b = base[(size_t)b * NW + M + jz];
      bp  = base + ((size_t)64 + b) * NW + M + jz;
    }
  } else if (isF) {
    f_p = px[(size_t)b * DIM + IN + jj];
    pp  = px + ((size_t)PER * BATCH + b) * DIM + IN + jj;
  }
  float* op = out + (size_t)b * SEQ * DIM + IN + (isF ? jj : 0);

  bar_lds();  // hF/hX zeros visible

#pragma unroll 1
  for (int n = 0; n < U; ++n) {
    const unsigned short c_p = f_p, c_b = f_b;
    const float c_pv = f_pv;

    // state pairs -> lane-resident reg (rz threads)
    unsigned hpk = 0u;
    if (isRZ) hpk = hX[t & 63];

    // ---- issue next-iteration prefetch (stays in flight across barriers)
    if (n + 1 < U) {
      if (isR) {
        f_p = *pp; pp += STRD;
        if constexpr (I > 0) {
          f_b = *bp; bp += (size_t)64 * NW;
          if (t < IN) { f_pv = *vp; vp += (size_t)PER * DIM; }
        }
      } else if (isRZ) {
        f_p = *pp; pp += STRD;
        if constexpr (I > 0) { f_b = *bp; bp += (size_t)64 * NW; }
      } else if (isF) {
        f_p = *pp; pp += STRD;
      }
    }

    // ---------------- phase A: r and z gates (readlane dots on hpk) -------
    if (isRZ) {
      float a0 = 0.f, a1 = 0.f, a2 = 0.f, a3 = 0.f;
#pragma unroll
      for (int k2 = 0; k2 < 64; k2 += 4) {
        a0 = dot2(w[k2],     bcast(hpk, k2),     a0);
        a1 = dot2(w[k2 + 1], bcast(hpk, k2 + 1), a1);
        a2 = dot2(w[k2 + 2], bcast(hpk, k2 + 2), a2);
        a3 = dot2(w[k2 + 3], bcast(hpk, k2 + 3), a3);
      }
      float a = bf2f(c_p) + (a0 + a1) + (a2 + a3);
      if constexpr (I > 0) a += bf2f(c_b);
      if (isR) {
        const float r = sigm(a);
        float hp;
        if constexpr (I == 0) hp = hF[t];
        else hp = (t >= IN) ? hF[t - IN] : c_pv;
        const float u  = r * hp;
        const float uo = __shfl_xor(u, 1);
        if (!(t & 1)) uX[t >> 1] = packbf(u, uo);
      } else {
        zX[jz] = sigm(a);
      }
    }
    bar_lds();  // bar1: uX, zX ready

    // ---------------- phase B: candidate matvec on u slice ----------------
    float ah = 0.f, zf = 0.f;
    if (!isRZ) {
      const unsigned upk = uX[(q << 6) | (t & 63)];
      if (isF) zf = zX[jj];  // early issue; needed after dots
      float a0 = 0.f, a1 = 0.f, a2 = 0.f, a3 = 0.f;
#pragma unroll
      for (int k2 = 0; k2 < 64; k2 += 4) {
        a0 = dot2(w[k2],     bcast(upk, k2),     a0);
        a1 = dot2(w[k2 + 1], bcast(upk, k2 + 1), a1);
        a2 = dot2(w[k2 + 2], bcast(upk, k2 + 2), a2);
        a3 = dot2(w[k2 + 3], bcast(upk, k2 + 3), a3);
      }
      ah = (a0 + a1) + (a2 + a3);
      if constexpr (NSL > 1) {
        if (q > 0) partX[(q - 1) * 128 + jj] = ah;
      }
    }
    if constexpr (NSL > 1) bar_lds();  // barB: partials ready

    // ---------------- finalize (slice-0 h-threads) ----------------
    if (isF) {
      float tot = ah;
      if constexpr (NSL > 1) {
#pragma unroll
        for (int i = 1; i < NSL; ++i) tot += partX[(i - 1) * 128 + jj];
      }
      const float hnew = sigm(tot + bf2f(c_p));
      const float v    = zf * hnew + (1.f - zf) * vprev;
      vprev = v;
      hF[jj] = v;
      const float vo = __shfl_xor(v, 1);
      if (!(jj & 1)) hX[jj >> 1] = packbf(v, vo);
#pragma unroll
      for (int p = 0; p < PER; ++p) op[p * DIM] = v;
    }
    op += (size_t)PER * DIM;
    bar_lds();  // bar2: hF/hX ready for next step
  }
}

// ---------------------------------------------------------------------------
// Kernel 4b: R1 scan_phase — retained for I=3 only (64 steps, proven).
// ---------------------------------------------------------------------------
template<int I, int TPB>
__global__ __launch_bounds__(TPB, 1) void scan_phase(
    const unsigned short* __restrict__ px,
    const unsigned short* __restrict__ pr,
    const unsigned short* __restrict__ pz,
    const unsigned* __restrict__ crpk,
    const unsigned* __restrict__ czpk,
    const unsigned* __restrict__ chpk,
    const unsigned short* __restrict__ base,
    float* __restrict__ out)
{
  constexpr int M   = (I + 1) * 128;
  constexpr int IN  = I * 128;
  constexpr int PER = 1 << I;
  constexpr int U   = 512 >> I;
  constexpr int NW  = M + 128;
  constexpr int HKP = M / 2;
  constexpr int SPL = (I == 0) ? 2 : 4;
  constexpr int HT  = HKP / SPL;
  constexpr int ZT  = 64 / SPL;
  constexpr int RTH = (M < TPB) ? M : TPB;

  __shared__ float    hS[128];
  __shared__ unsigned hPk[64];
  __shared__ unsigned uPk[HKP];

  const int b  = blockIdx.x;
  const int t  = threadIdx.x;
  const int jh = t / SPL;
  const int q  = t % SPL;
  const bool hasR = (t < RTH);
  const int col0 = t;

  unsigned wr0[64];
  if (hasR) {
#pragma unroll
    for (int k2 = 0; k2 < 64; ++k2) wr0[k2] = crpk[k2 * M + col0];
  }
  unsigned wz[ZT];
#pragma unroll
  for (int k2 = 0; k2 < ZT; ++k2) wz[k2] = czpk[(q * ZT + k2) * 128 + jh];
  unsigned wh[HT];
#pragma unroll
  for (int k2 = 0; k2 < HT; ++k2) wh[k2] = chpk[(q * HT + k2) * 128 + jh];

  if (t < 128) hS[t] = 0.f;
  if (t < 64)  hPk[t] = 0u;
  float vprev = 0.f;

  unsigned short f_pr = 0, f_pz = 0, f_px = 0, f_br = 0, f_bz = 0;
  float f_pv = 0.f;
  {
    f_pz = (pz + (size_t)b * DIM)[IN + jh];
    f_px = (px + (size_t)b * DIM)[IN + jh];
    if (hasR) f_pr = (pr + (size_t)b * DIM)[col0];
    if constexpr (I > 0) {
      const unsigned short* baseR = base + (size_t)b * NW;
      if (hasR) f_br = baseR[col0];
      f_bz = baseR[M + jh];
    }
  }

  bar_lds();

  for (int n = 0; n < U; ++n) {
    const int s = n * PER;
    const unsigned short c_pr = f_pr, c_pz = f_pz, c_px = f_px;
    const unsigned short c_br = f_br, c_bz = f_bz;
    const float c_pv = f_pv;

    {
      const int n2 = (n + 1 < U) ? (n + 1) : n;
      const int s2 = n2 * PER;
      f_pz = (pz + ((size_t)(s2 * BATCH + b)) * DIM)[IN + jh];
      f_px = (px + ((size_t)(s2 * BATCH + b)) * DIM)[IN + jh];
      if (hasR) f_pr = (pr + ((size_t)(s2 * BATCH + b)) * DIM)[col0];
      if constexpr (I > 0) {
        const unsigned short* baseR = base + (size_t)(n2 * 64 + b) * NW;
        if (hasR) f_br = baseR[col0];
        f_bz = baseR[M + jh];
        if (hasR && col0 < IN)
          f_pv = (out + ((size_t)b * SEQ + (s2 - 1)) * DIM)[col0];
      }
    }

    float az0 = 0.f, az1 = 0.f;
#pragma unroll
    for (int k2 = 0; k2 < ZT; k2 += 2) {
      az0 = dot2(wz[k2],     hPk[q * ZT + k2],     az0);
      az1 = dot2(wz[k2 + 1], hPk[q * ZT + k2 + 1], az1);
    }
    float az = az0 + az1;
    az += __shfl_xor(az, 1);
    if constexpr (SPL == 4) az += __shfl_xor(az, 2);
    float zpre = bf2f(c_pz) + az;
    if constexpr (I > 0) zpre += bf2f(c_bz);
    const float zg = sigm(zpre);

    float u = 0.f;
    if (hasR) {
      float a0 = 0.f, a1 = 0.f, a2 = 0.f, a3 = 0.f;
#pragma unroll
      for (int k2 = 0; k2 < 64; k2 += 4) {
        a0 = dot2(wr0[k2],     hPk[k2],     a0);
        a1 = dot2(wr0[k2 + 1], hPk[k2 + 1], a1);
        a2 = dot2(wr0[k2 + 2], hPk[k2 + 2], a2);
        a3 = dot2(wr0[k2 + 3], hPk[k2 + 3], a3);
      }
      float ar = bf2f(c_pr) + (a0 + a1) + (a2 + a3);
      if constexpr (I > 0) ar += bf2f(c_br);
      const float r = sigm(ar);
      float hp;
      if constexpr (I == 0) hp = hS[col0];
      else hp = (col0 >= IN) ? hS[col0 - IN] : (n > 0 ? c_pv : 0.f);
      u = r * hp;
    }
    const float uo = __shfl_xor(u, 1);
    if (hasR && !(t & 1)) uPk[t >> 1] = packbf(u, uo);

    bar_lds();

    float ah0 = 0.f, ah1 = 0.f, ah2 = 0.f, ah3 = 0.f;
    {
      const int o = q * HT;
#pragma unroll
      for (int k2 = 0; k2 < HT; k2 += 4) {
        ah0 = dot2(wh[k2],     uPk[o + k2],     ah0);
        ah1 = dot2(wh[k2 + 1], uPk[o + k2 + 1], ah1);
        ah2 = dot2(wh[k2 + 2], uPk[o + k2 + 2], ah2);
        ah3 = dot2(wh[k2 + 3], uPk[o + k2 + 3], ah3);
      }
    }
    float ah = (ah0 + ah1) + (ah2 + ah3);
    ah += __shfl_xor(ah, 1);
    if constexpr (SPL == 4) ah += __shfl_xor(ah, 2);
    const float hnew = sigm(ah + bf2f(c_px));
    const float v = zg * hnew + (1.f - zg) * vprev;
    vprev = v;

    if (q == 0) hS[jh] = v;
    const float vp = __shfl_xor(v, SPL);
    if ((t & (2 * SPL - 1)) == 0) hPk[t / (2 * SPL)] = packbf(v, vp);

    float* orow = out + ((size_t)b * SEQ + s) * DIM + IN + jh;
#pragma unroll
    for (int p = q; p < PER; p += SPL) orow[p * DIM] = v;

    bar_lds();
  }
}

// ---------------------------------------------------------------------------
// Host launcher
// ---------------------------------------------------------------------------
extern "C" void kernel_launch(void* const* d_in, const int* in_sizes, int n_in,
                              void* d_out, int out_size, void* d_ws, size_t ws_size,
                              hipStream_t stream) {
  (void)in_sizes; (void)n_in; (void)out_size; (void)ws_size;

  const float* x  = (const float*)d_in[0];
  const float* W  = (const float*)d_in[1];
  const float* bb = (const float*)d_in[2];
  const float* Wr = (const float*)d_in[3];
  const float* br = (const float*)d_in[4];
  const float* Wz = (const float*)d_in[5];
  const float* bz = (const float*)d_in[6];
  const float* ch_[4]; const float* cr_[4]; const float* cz_[4];
  for (int i = 0; i < 4; ++i) {
    ch_[i] = (const float*)d_in[7 + 3 * i];
    cr_[i] = (const float*)d_in[8 + 3 * i];
    cz_[i] = (const float*)d_in[9 + 3 * i];
  }

  char* ws = (char*)d_ws;
  size_t off = 0;
  auto alloc = [&](size_t bytes) -> void* {
    void* p = ws + off;
    off += (bytes + 255) & ~(size_t)255;
    return p;
  };

  unsigned short* WbT = (unsigned short*)alloc(3ull * 512 * 512 * 2);
  unsigned* Crpk[4]; unsigned* Chpk[4]; unsigned* Czpk[4];
  unsigned short* Bcat[4] = {nullptr, nullptr, nullptr, nullptr};
  for (int i = 0; i < 4; ++i) {
    int m = (i + 1) * 128;
    Crpk[i] = (unsigned*)alloc((size_t)64 * m * 4);
    Chpk[i] = (unsigned*)alloc((size_t)(m / 2) * 128 * 4);
    Czpk[i] = (unsigned*)alloc((size_t)64 * 128 * 4);
  }
  for (int i = 1; i < 4; ++i) {
    int m = (i + 1) * 128, iN = i * 128;
    Bcat[i] = (unsigned short*)alloc((size_t)(m + 128) * iN * 2);
  }
  unsigned short* p0 = (unsigned short*)alloc((size_t)SEQ * BATCH * DIM * 2);
  unsigned short* p1 = (unsigned short*)alloc((size_t)SEQ * BATCH * DIM * 2);
  unsigned short* p2 = (unsigned short*)alloc((size_t)SEQ * BATCH * DIM * 2);
  unsigned short* baseB = (unsigned short*)alloc((size_t)16384 * 384 * 2);  // max of G1..G3
  // total ~117 MB

  // ---- cast/pack jobs
  CastJobs jobs{};
  int jn = 0;
  const float* wsrc[3] = {W, Wr, Wz};
  for (int j = 0; j < 3; ++j) {
    jobs.src[jn] = wsrc[j]; jobs.dst[jn] = WbT + (size_t)j * 512 * 512;
    jobs.n[jn] = 512 * 512; jobs.mode[jn] = 1; jobs.m[jn] = 512; jobs.iN[jn] = 0; jn++;
  }
  for (int i = 0; i < 4; ++i) {
    int m = (i + 1) * 128, iN = i * 128;
    jobs.src[jn] = cr_[i]; jobs.dst[jn] = Crpk[i];
    jobs.n[jn] = 64 * m; jobs.mode[jn] = 3; jobs.m[jn] = m; jobs.iN[jn] = iN; jn++;
    jobs.src[jn] = ch_[i]; jobs.dst[jn] = Chpk[i];
    jobs.n[jn] = (m / 2) * 128; jobs.mode[jn] = 4; jobs.m[jn] = m; jobs.iN[jn] = iN; jn++;
    jobs.src[jn] = cz_[i]; jobs.dst[jn] = Czpk[i];
    jobs.n[jn] = 64 * 128; jobs.mode[jn] = 5; jobs.m[jn] = m; jobs.iN[jn] = iN; jn++;
  }
  for (int i = 1; i < 4; ++i) {
    int m = (i + 1) * 128, iN = i * 128;
    jobs.src[jn] = cr_[i]; jobs.src2[jn] = cz_[i]; jobs.dst[jn] = Bcat[i];
    jobs.n[jn] = (m + 128) * iN; jobs.mode[jn] = 6; jobs.m[jn] = m; jobs.iN[jn] = iN; jn++;
  }
  cast_kernel<<<256, 256, 0, stream>>>(jobs);

  // ---- projections
  proj_kernel<<<SEQ * 12, 256, 0, stream>>>(x, WbT, bb, br, bz, p0, p1, p2);

  float* outp = (float*)d_out;

  // ---- cascade: B0 -> G1 -> B1 -> G2 -> B2 -> G3 -> B3
  scan_rl2<0><<<64, 384, 0, stream>>>(p0, p1, p2, Crpk[0], Czpk[0], Chpk[0],
                                      nullptr, outp);
  base_gemm<1><<<256 * 3, 256, 0, stream>>>(outp, Bcat[1], baseB);
  scan_rl2<1><<<64, 640, 0, stream>>>(p0, p1, p2, Crpk[1], Czpk[1], Chpk[1],
                                      baseB, outp);
  base_gemm<2><<<128 * 4, 256, 0, stream>>>(outp, Bcat[2], baseB);
  scan_rl2<2><<<64, 896, 0, stream>>>(p0, p1, p2, Crpk[2], Czpk[2], Chpk[2],
                                      baseB, outp);
  base_gemm<3><<<64 * 5, 256, 0, stream>>>(outp, Bcat[3], baseB);
  scan_phase<3, 512><<<64, 512, 0, stream>>>(p0, p1, p2, Crpk[3], Czpk[3],
                                             Chpk[3], baseB, outp);
}